// Round 7
// baseline (323.314 us; speedup 1.0000x reference)
//
#include <hip/hip_runtime.h>
#include <math.h>

#define CC 96
#define NP 4096
#define NHEADS 6
#define NELEMF 393216.0f
#define EPSF 1e-5f

typedef __attribute__((ext_vector_type(8))) short bf16x8;
typedef __attribute__((ext_vector_type(4))) float f32x4;
#define MFMA16(a,b,c) __builtin_amdgcn_mfma_f32_16x16x32_bf16(a,b,c,0,0,0)

// ---- workspace layout (float offsets) ----
#define WS_STATS 0
#define WQKV1  64
#define WQKV2  (WQKV1+13824)
#define WPROJ1 (WQKV2+13824)
#define WPROJ2 (WPROJ1+4608)
#define WMLP1  (WPROJ2+4608)
#define WMLP2  (WMLP1+18432)
#define WM2A1  (WMLP2+18432)
#define WM2A2  (WM2A1+4608)
#define WPA1T  (WM2A2+4608)
#define WBNS   (WPA1T+1152)
#define WS_Q   870784
#define WS_K   (WS_Q+786432)
#define WS_V   (WS_K+786432)
#define WS_ATTPM (WS_V+786432)
#define WS_X1  (WS_ATTPM+786432)  // hid (bf16 16384x384) reuses WS_Q..WS_X1
#define WS_X2  (WS_X1+1572864)
#define WS_X3  (WS_X2+1572864)
#define WS_PA  (WS_X3+1572864)
#define WS_GAP (WS_PA+16384)
#define WS_CA  (WS_GAP+384)

__device__ __forceinline__ float gelu_f(float x){
  return 0.5f * x * (1.0f + erff(x * 0.7071067811865476f));
}
__device__ __forceinline__ float sigmoid_f(float x){
  return 1.0f / (1.0f + __expf(-x));
}
__device__ __forceinline__ unsigned short bfr(float f){
  unsigned int u = __float_as_uint(f);
  u += 0x7fffu + ((u >> 16) & 1u);
  return (unsigned short)(u >> 16);
}
__device__ __forceinline__ float bflo(unsigned int u){ return __uint_as_float(u << 16); }
__device__ __forceinline__ float bfhi(unsigned int u){ return __uint_as_float(u & 0xffff0000u); }
__device__ __forceinline__ void get_ms(const float* st, int b, float& mean, float& inv, float& stdv){
  float s = st[b], s2 = st[4+b];
  mean = s * (1.0f/NELEMF);
  float var = fmaxf(s2 * (1.0f/NELEMF) - mean*mean, 0.0f);
  stdv = sqrtf(var + EPSF);
  inv = 1.0f / stdv;
}

// ---- per-batch sum/sumsq over input x ----
__global__ void stats_kernel(const float* __restrict__ src, float* __restrict__ st){
  int b = blockIdx.x / CC, c = blockIdx.x % CC;
  const float* p = src + (b*CC + c)*NP;
  float s = 0.f, s2 = 0.f;
  for(int i = threadIdx.x; i < NP; i += 256){ float v = p[i]; s += v; s2 = fmaf(v, v, s2); }
  for(int off = 32; off > 0; off >>= 1){ s += __shfl_down(s, off); s2 += __shfl_down(s2, off); }
  __shared__ float ls[8];
  int wid = threadIdx.x >> 6;
  if((threadIdx.x & 63) == 0){ ls[wid] = s; ls[4+wid] = s2; }
  __syncthreads();
  if(threadIdx.x == 0){
    atomicAdd(&st[b],   ls[0]+ls[1]+ls[2]+ls[3]);
    atomicAdd(&st[4+b], ls[4]+ls[5]+ls[6]+ls[7]);
  }
}

// ---- convert all weights to bf16 W^T[n][k]; BN scale/shift; pa1 transpose ----
__global__ void prep_weights(const float* __restrict__ q1, const float* __restrict__ q2,
                             const float* __restrict__ p1, const float* __restrict__ p2,
                             const float* __restrict__ w1, const float* __restrict__ w2,
                             const float* __restrict__ a1, const float* __restrict__ a2,
                             const float* __restrict__ pw1,
                             const float* __restrict__ bg, const float* __restrict__ bb,
                             const float* __restrict__ bm, const float* __restrict__ bv,
                             float* __restrict__ ws){
  int gid = blockIdx.x*256 + threadIdx.x;
  if(gid < 27648){ int n = gid/96, c = gid%96; ((unsigned short*)(ws+WQKV1))[gid] = bfr(q1[c*288+n]); }
  else if(gid < 55296){ int g = gid-27648; int n = g/96, c = g%96; ((unsigned short*)(ws+WQKV2))[g] = bfr(q2[c*288+n]); }
  else if(gid < 64512){ int g = gid-55296; int n = g/96, c = g%96; ((unsigned short*)(ws+WPROJ1))[g] = bfr(p1[c*96+n]); }
  else if(gid < 73728){ int g = gid-64512; int n = g/96, c = g%96; ((unsigned short*)(ws+WPROJ2))[g] = bfr(p2[c*96+n]); }
  else if(gid < 110592){ int g = gid-73728; ((unsigned short*)(ws+WMLP1))[g] = bfr(w1[g]); }
  else if(gid < 147456){ int g = gid-110592; ((unsigned short*)(ws+WMLP2))[g] = bfr(w2[g]); }
  else if(gid < 156672){ int g = gid-147456; ((unsigned short*)(ws+WM2A1))[g] = bfr(a1[g]); }
  else if(gid < 165888){ int g = gid-156672; ((unsigned short*)(ws+WM2A2))[g] = bfr(a2[g]); }
  else if(gid < 167040){ int g = gid-165888; int c = g/12, h = g%12; ws[WPA1T + g] = pw1[h*96+c]; }
  else if(gid < 167136){ int c = gid-167040;
    float sc = rsqrtf(bv[c] + EPSF) * bg[c];
    ws[WBNS + c] = sc;
    ws[WBNS + 96 + c] = bb[c] - bm[c]*sc;
  }
}

// ---- fused LN + QKV GEMM: M=64-px block, all 288 N, A read once ----
__global__ void __launch_bounds__(256) gemm_qkv_kernel(
    const float* __restrict__ xin, const float* __restrict__ st,
    const float* __restrict__ lnw, const float* __restrict__ lnb,
    const unsigned short* __restrict__ wT, const float* __restrict__ qb,
    unsigned short* __restrict__ qo, unsigned short* __restrict__ ko, unsigned short* __restrict__ vo){
  __shared__ unsigned short Atl[64*104];
  __shared__ float scl[96], ofs[96];
  int m_base = blockIdx.x*64;
  int b = m_base >> 12, pxl0 = m_base & 4095;
  float mean, inv, stdv; get_ms(st, b, mean, inv, stdv);
  int tid = threadIdx.x;
  if(tid < 96){ float s = inv*lnw[tid]; scl[tid] = s; ofs[tid] = lnb[tid] - mean*s; }
  __syncthreads();
  const float* src = xin + (size_t)b*CC*NP + pxl0;
  for(int idx = tid; idx < 96*64; idx += 256){
    int c = idx >> 6, p = idx & 63;
    Atl[p*104 + c] = bfr(fmaf(src[c*NP + p], scl[c], ofs[c]));
  }
  __syncthreads();
  int w = tid >> 6, lane = tid & 63, ml = lane & 15, q = lane >> 4;
  const unsigned short* arow = Atl + (w*16 + ml)*104;
  bf16x8 av[3];
  #pragma unroll
  for(int ks = 0; ks < 3; ++ks) av[ks] = *(const bf16x8*)(arow + ks*32 + q*8);
  f32x4 z = {0.f,0.f,0.f,0.f};
  #pragma unroll
  for(int g = 0; g < 6; ++g){
    f32x4 acc[3] = {z, z, z};
    #pragma unroll
    for(int ks = 0; ks < 3; ++ks){
      #pragma unroll
      for(int gg = 0; gg < 3; ++gg){
        bf16x8 bv = *(const bf16x8*)(wT + (g*48 + gg*16 + ml)*96 + ks*32 + q*8);
        acc[gg] = MFMA16(av[ks], bv, acc[gg]);
      }
    }
    #pragma unroll
    for(int gg = 0; gg < 3; ++gg){
      int nfb = g*48 + gg*16;
      int t = nfb/96, head = (nfb%96) >> 4;
      float scale = (t == 0) ? 0.25f : 1.0f;
      unsigned short* dst = (t == 0) ? qo : (t == 1) ? ko : vo;
      float bias = qb[nfb + ml];
      #pragma unroll
      for(int r = 0; r < 4; ++r){
        int pxl = pxl0 + w*16 + q*4 + r;
        dst[(((size_t)(b*NHEADS + head))*NP + pxl)*16 + ml] = bfr((acc[gg][r] + bias)*scale);
      }
    }
  }
}

// ---- proj GEMM: attpm @ projT -> c-major + residual + fused stats (M=128) ----
__global__ void __launch_bounds__(256) gemm_proj_kernel(
    const unsigned short* __restrict__ attpm, const unsigned short* __restrict__ wT,
    const float* __restrict__ pb, const float* __restrict__ scx, const float* __restrict__ st,
    const float* __restrict__ m1w, const float* __restrict__ m1b,
    const float* __restrict__ m2w, const float* __restrict__ m2b,
    float* __restrict__ dst, float* __restrict__ st_out){
  int w = threadIdx.x >> 6, lane = threadIdx.x & 63;
  int ml = lane & 15, q = lane >> 4;
  int m_base = blockIdx.x*128 + w*32;
  int n0 = blockIdx.y*48;
  f32x4 acc[2][3];
  f32x4 z = {0.f,0.f,0.f,0.f};
  #pragma unroll
  for(int f=0; f<2; ++f) for(int g=0; g<3; ++g) acc[f][g] = z;
  {
    const bf16x8* a0 = (const bf16x8*)(attpm + (size_t)(m_base + ml)*96 + q*8);
    const bf16x8* a1 = (const bf16x8*)(attpm + (size_t)(m_base + 16 + ml)*96 + q*8);
    #pragma unroll
    for(int ks = 0; ks < 3; ++ks){
      bf16x8 av0 = a0[ks*4], av1 = a1[ks*4];
      #pragma unroll
      for(int g = 0; g < 3; ++g){
        bf16x8 bv = *(const bf16x8*)(wT + (n0 + g*16 + ml)*96 + ks*32 + q*8);
        acc[0][g] = MFMA16(av0, bv, acc[0][g]);
        acc[1][g] = MFMA16(av1, bv, acc[1][g]);
      }
    }
  }
  __shared__ float T[48*133];
  #pragma unroll
  for(int f = 0; f < 2; ++f)
    #pragma unroll
    for(int g = 0; g < 3; ++g)
      #pragma unroll
      for(int r = 0; r < 4; ++r)
        T[(g*16 + ml)*133 + w*32 + f*16 + q*4 + r] = acc[f][g][r];
  __syncthreads();
  int b = (blockIdx.x*128) >> 12, pxl0 = (blockIdx.x*128) & 4095;
  float mean, inv, stdv; get_ms(st, b, mean, inv, stdv);
  float s = 0.f, s2 = 0.f;
  for(int idx = threadIdx.x; idx < 48*128; idx += 256){
    int row = idx >> 7, px = idx & 127;
    int n = n0 + row;
    float rsf = fmaf(m1w[n], stdv, m1b[n]);
    float rbf = fmaf(m2w[n], mean, m2b[n]);
    int ad = (b*CC + n)*NP + pxl0 + px;
    float val = scx[ad] + (T[row*133 + px] + pb[n])*rsf + rbf;
    dst[ad] = val;
    s += val; s2 = fmaf(val, val, s2);
  }
  for(int off = 32; off > 0; off >>= 1){ s += __shfl_down(s, off); s2 += __shfl_down(s2, off); }
  __shared__ float ls[8];
  int wid = threadIdx.x >> 6;
  if((threadIdx.x & 63) == 0){ ls[wid] = s; ls[4+wid] = s2; }
  __syncthreads();
  if(threadIdx.x == 0){
    atomicAdd(&st_out[b],   ls[0]+ls[1]+ls[2]+ls[3]);
    atomicAdd(&st_out[4+b], ls[4]+ls[5]+ls[6]+ls[7]);
  }
}

// ---- fused LN + mlp1 GEMM: M=64, all 384 N -> relu -> hid bf16 [16384][384] ----
__global__ void __launch_bounds__(256) gemm_mlp1_kernel(
    const float* __restrict__ xin, const float* __restrict__ st,
    const float* __restrict__ lnw, const float* __restrict__ lnb,
    const unsigned short* __restrict__ wT, const float* __restrict__ b1,
    unsigned short* __restrict__ hid){
  __shared__ unsigned short Atl[64*104];
  __shared__ float scl[96], ofs[96];
  int m_base = blockIdx.x*64;
  int b = m_base >> 12, pxl0 = m_base & 4095;
  float mean, inv, stdv; get_ms(st, b, mean, inv, stdv);
  int tid = threadIdx.x;
  if(tid < 96){ float s = inv*lnw[tid]; scl[tid] = s; ofs[tid] = lnb[tid] - mean*s; }
  __syncthreads();
  const float* src = xin + (size_t)b*CC*NP + pxl0;
  for(int idx = tid; idx < 96*64; idx += 256){
    int c = idx >> 6, p = idx & 63;
    Atl[p*104 + c] = bfr(fmaf(src[c*NP + p], scl[c], ofs[c]));
  }
  __syncthreads();
  int w = tid >> 6, lane = tid & 63, ml = lane & 15, q = lane >> 4;
  const unsigned short* arow = Atl + (w*16 + ml)*104;
  bf16x8 av[3];
  #pragma unroll
  for(int ks = 0; ks < 3; ++ks) av[ks] = *(const bf16x8*)(arow + ks*32 + q*8);
  f32x4 z = {0.f,0.f,0.f,0.f};
  #pragma unroll
  for(int g = 0; g < 8; ++g){
    f32x4 acc[3] = {z, z, z};
    #pragma unroll
    for(int ks = 0; ks < 3; ++ks){
      #pragma unroll
      for(int gg = 0; gg < 3; ++gg){
        bf16x8 bv = *(const bf16x8*)(wT + (g*48 + gg*16 + ml)*96 + ks*32 + q*8);
        acc[gg] = MFMA16(av[ks], bv, acc[gg]);
      }
    }
    #pragma unroll
    for(int gg = 0; gg < 3; ++gg){
      int n = g*48 + gg*16 + ml;
      float bias = b1[n];
      #pragma unroll
      for(int r = 0; r < 4; ++r){
        int m = m_base + w*16 + q*4 + r;
        hid[(size_t)m*384 + n] = bfr(fmaxf(acc[gg][r] + bias, 0.f));
      }
    }
  }
}

// ---- mlp2 GEMM (K=384): hid @ mlp2T -> c-major + residual(x1) via st2 ----
__global__ void __launch_bounds__(256) gemm_mlp2_kernel(
    const unsigned short* __restrict__ hid, const unsigned short* __restrict__ wT,
    const float* __restrict__ b2, const float* __restrict__ scx, const float* __restrict__ st,
    const float* __restrict__ m1w, const float* __restrict__ m1b,
    const float* __restrict__ m2w, const float* __restrict__ m2b,
    float* __restrict__ dst){
  int w = threadIdx.x >> 6, lane = threadIdx.x & 63;
  int ml = lane & 15, q = lane >> 4;
  int m_base = blockIdx.x*128 + w*32;
  int n0 = blockIdx.y*48;
  f32x4 acc[2][3];
  f32x4 z = {0.f,0.f,0.f,0.f};
  #pragma unroll
  for(int f=0; f<2; ++f) for(int g=0; g<3; ++g) acc[f][g] = z;
  {
    const bf16x8* a0 = (const bf16x8*)(hid + (size_t)(m_base + ml)*384 + q*8);
    const bf16x8* a1 = (const bf16x8*)(hid + (size_t)(m_base + 16 + ml)*384 + q*8);
    #pragma unroll
    for(int ks = 0; ks < 12; ++ks){
      bf16x8 av0 = a0[ks*4], av1 = a1[ks*4];
      #pragma unroll
      for(int g = 0; g < 3; ++g){
        bf16x8 bv = *(const bf16x8*)(wT + (n0 + g*16 + ml)*384 + ks*32 + q*8);
        acc[0][g] = MFMA16(av0, bv, acc[0][g]);
        acc[1][g] = MFMA16(av1, bv, acc[1][g]);
      }
    }
  }
  __shared__ float T[48*133];
  #pragma unroll
  for(int f = 0; f < 2; ++f)
    #pragma unroll
    for(int g = 0; g < 3; ++g)
      #pragma unroll
      for(int r = 0; r < 4; ++r)
        T[(g*16 + ml)*133 + w*32 + f*16 + q*4 + r] = acc[f][g][r];
  __syncthreads();
  int b = (blockIdx.x*128) >> 12, pxl0 = (blockIdx.x*128) & 4095;
  float mean, inv, stdv; get_ms(st, b, mean, inv, stdv);
  for(int idx = threadIdx.x; idx < 48*128; idx += 256){
    int row = idx >> 7, px = idx & 127;
    int n = n0 + row;
    float rsf = fmaf(m1w[n], stdv, m1b[n]);
    float rbf = fmaf(m2w[n], mean, m2b[n]);
    int ad = (b*CC + n)*NP + pxl0 + px;
    dst[ad] = scx[ad] + (T[row*133 + px] + b2[n])*rsf + rbf;
  }
}

// ---- fused m2a: BN*pa*ca load -> GEMM1 -> gelu(LDS) -> GEMM2 -> +x3 -> out (M=64) ----
__global__ void __launch_bounds__(256) gemm_m2a_kernel(
    const float* __restrict__ x3, const float* __restrict__ bns,
    const float* __restrict__ pa, const float* __restrict__ ca,
    const unsigned short* __restrict__ w1T, const float* __restrict__ b1,
    const unsigned short* __restrict__ w2T, const float* __restrict__ b2,
    const float* __restrict__ scx, float* __restrict__ outp){
  __shared__ __align__(16) char smbuf[26624];
  __shared__ float scl[96], ofs[96], pal[64];
  unsigned short* Atl = (unsigned short*)smbuf;            // [0, 13312)
  unsigned short* tl2 = (unsigned short*)(smbuf + 13312);  // [13312, 26624)
  float* T = (float*)smbuf;                                // aliases all, used last
  int m_base = blockIdx.x*64;
  int b = m_base >> 12, pxl0 = m_base & 4095;
  int tid = threadIdx.x;
  if(tid < 96){ float cv = ca[b*96 + tid]; scl[tid] = bns[tid]*cv; ofs[tid] = bns[96+tid]*cv; }
  if(tid >= 128 && tid < 192) pal[tid-128] = pa[m_base + (tid-128)];
  __syncthreads();
  const float* src = x3 + (size_t)b*CC*NP + pxl0;
  for(int idx = tid; idx < 96*64; idx += 256){
    int c = idx >> 6, p = idx & 63;
    Atl[p*104 + c] = bfr(fmaf(src[c*NP + p], scl[c], ofs[c]) * pal[p]);
  }
  __syncthreads();
  int w = tid >> 6, lane = tid & 63, ml = lane & 15, q = lane >> 4;
  f32x4 z = {0.f,0.f,0.f,0.f};
  f32x4 acc1[6];
  #pragma unroll
  for(int g=0; g<6; ++g) acc1[g] = z;
  {
    const unsigned short* arow = Atl + (w*16 + ml)*104;
    #pragma unroll
    for(int ks = 0; ks < 3; ++ks){
      bf16x8 av = *(const bf16x8*)(arow + ks*32 + q*8);
      #pragma unroll
      for(int g = 0; g < 6; ++g){
        bf16x8 bv = *(const bf16x8*)(w1T + (g*16 + ml)*96 + ks*32 + q*8);
        acc1[g] = MFMA16(av, bv, acc1[g]);
      }
    }
  }
  #pragma unroll
  for(int g = 0; g < 6; ++g){
    float bias = b1[g*16 + ml];
    #pragma unroll
    for(int r = 0; r < 4; ++r)
      tl2[(w*16 + q*4 + r)*104 + g*16 + ml] = bfr(gelu_f(acc1[g][r] + bias));
  }
  __syncthreads();
  f32x4 acc2[6];
  #pragma unroll
  for(int g=0; g<6; ++g) acc2[g] = z;
  {
    const unsigned short* arow = tl2 + (w*16 + ml)*104;
    #pragma unroll
    for(int ks = 0; ks < 3; ++ks){
      bf16x8 av = *(const bf16x8*)(arow + ks*32 + q*8);
      #pragma unroll
      for(int g = 0; g < 6; ++g){
        bf16x8 bv = *(const bf16x8*)(w2T + (g*16 + ml)*96 + ks*32 + q*8);
        acc2[g] = MFMA16(av, bv, acc2[g]);
      }
    }
  }
  __syncthreads();   // all tl2 reads done; smbuf becomes T
  #pragma unroll
  for(int g = 0; g < 6; ++g)
    #pragma unroll
    for(int r = 0; r < 4; ++r)
      T[(g*16 + ml)*68 + w*16 + q*4 + r] = acc2[g][r];
  __syncthreads();
  for(int idx = tid; idx < 96*64; idx += 256){
    int n = idx >> 6, p = idx & 63;
    int ad = (b*CC + n)*NP + pxl0 + p;
    outp[ad] = scx[ad] + T[n*68 + p] + b2[n];
  }
}

// ---- neighborhood attention: bf16 LDS-staged k/v, output pixel-major bf16 ----
template<int K, int D, int RPB>
__global__ void __launch_bounds__(256) attn_kernel(
    const unsigned short* __restrict__ qb, const unsigned short* __restrict__ kb,
    const unsigned short* __restrict__ vb, const float* __restrict__ rpb,
    unsigned short* __restrict__ outp){
  int bh = blockIdx.x >> 6;
  int x = blockIdx.x & 63;
  int head = bh % NHEADS, b = bh / NHEADS;

  int gx = x % D, px = x / D;
  int Lgx = (64 - gx + D - 1) / D;
  int sx = min(max(px - K/2, 0), Lgx - K);

  __shared__ unsigned int sm[2*K*512];
  unsigned int* kl = sm;
  unsigned int* vl = sm + K*512;
  const unsigned int* kg = (const unsigned int*)(kb + (size_t)bh*NP*16);
  const unsigned int* vg = (const unsigned int*)(vb + (size_t)bh*NP*16);
  int tid = threadIdx.x;
  #pragma unroll
  for(int i = 0; i < K; ++i){
    int hh = gx + D*(sx + i);
    ((uint2*)(kl + i*512))[tid] = ((const uint2*)(kg + hh*512))[tid];
    ((uint2*)(vl + i*512))[tid] = ((const uint2*)(vg + hh*512))[tid];
  }
  __syncthreads();

  int pixoff = tid >> 2, t = tid & 3;
  int y = pixoff;
  int pix = x*64 + y;
  uint2 qd = *(const uint2*)(qb + ((size_t)bh*NP + pix)*16 + 4*t);
  float qx = bflo(qd.x), qy = bfhi(qd.x), qz = bflo(qd.y), qw = bfhi(qd.y);

  int gy = y % D, py = y / D;
  int Lgy = (64 - gy + D - 1) / D;
  int sy = min(max(py - K/2, 0), Lgy - K);

  float sc[K*K];
  #pragma unroll
  for(int i = 0; i < K; ++i){
    #pragma unroll
    for(int j = 0; j < K; ++j){
      int ww = gy + D*(sy + j);
      uint2 kv = *(const uint2*)(kl + i*512 + ww*8 + t*2);
      float s = qx*bflo(kv.x);
      s = fmaf(qy, bfhi(kv.x), s);
      s = fmaf(qz, bflo(kv.y), s);
      s = fmaf(qw, bfhi(kv.y), s);
      sc[i*K + j] = s;
    }
  }
  float mx = -1e30f;
  #pragma unroll
  for(int i = 0; i < K; ++i){
    const float* brow = rpb + (head*RPB + (sx + i - px + (K-1)))*RPB + (sy - py + (K-1));
    #pragma unroll
    for(int j = 0; j < K; ++j){
      float s = sc[i*K + j];
      s += __shfl_xor(s, 1);
      s += __shfl_xor(s, 2);
      s += brow[j];
      sc[i*K + j] = s;
      mx = fmaxf(mx, s);
    }
  }
  float sum = 0.f;
  #pragma unroll
  for(int n = 0; n < K*K; ++n){ float e = __expf(sc[n] - mx); sc[n] = e; sum += e; }
  float rs = 1.0f / sum;
  float4 acc = {0,0,0,0};
  #pragma unroll
  for(int i = 0; i < K; ++i){
    #pragma unroll
    for(int j = 0; j < K; ++j){
      int ww = gy + D*(sy + j);
      float wgt = sc[i*K + j] * rs;
      uint2 vv = *(const uint2*)(vl + i*512 + ww*8 + t*2);
      acc.x = fmaf(wgt, bflo(vv.x), acc.x);
      acc.y = fmaf(wgt, bfhi(vv.x), acc.y);
      acc.z = fmaf(wgt, bflo(vv.y), acc.z);
      acc.w = fmaf(wgt, bfhi(vv.y), acc.w);
    }
  }
  ushort4 o4;
  o4.x = bfr(acc.x); o4.y = bfr(acc.y); o4.z = bfr(acc.z); o4.w = bfr(acc.w);
  *(ushort4*)(outp + ((size_t)(b*NP + pix))*96 + head*16 + 4*t) = o4;
}

// ---- fused pixel-attention + gap partial accumulation ----
__global__ void __launch_bounds__(256) pa_gap_kernel(
    const float* __restrict__ x3, const float* __restrict__ bns,
    const float* __restrict__ w1t, const float* __restrict__ b1,
    const float* __restrict__ w2, const float* __restrict__ b2,
    float* __restrict__ pa, float* __restrict__ gap){
  int b = blockIdx.x >> 4;
  int p = (blockIdx.x & 15)*256 + threadIdx.x;
  float acc[12];
  #pragma unroll
  for(int h = 0; h < 12; ++h) acc[h] = b1[h];
  #pragma unroll 8
  for(int c = 0; c < CC; ++c){
    float yv = fmaf(x3[(b*CC + c)*NP + p], bns[c], bns[96 + c]);
    #pragma unroll
    for(int h = 0; h < 12; ++h) acc[h] = fmaf(yv, w1t[c*12 + h], acc[h]);
  }
  float s = b2[0];
  #pragma unroll
  for(int h = 0; h < 12; ++h) s = fmaf(gelu_f(acc[h]), w2[h], s);
  float pav = sigmoid_f(s);
  pa[b*NP + p] = pav;
  // gap partials: re-read L2-hot x3, wave-reduce per channel
  __shared__ float gpart[4*96];
  int lane = threadIdx.x & 63, wid = threadIdx.x >> 6;
  for(int c = 0; c < CC; ++c){
    float t = fmaf(x3[(b*CC + c)*NP + p], bns[c], bns[96 + c]) * pav;
    t += __shfl_xor(t, 1);  t += __shfl_xor(t, 2);  t += __shfl_xor(t, 4);
    t += __shfl_xor(t, 8);  t += __shfl_xor(t, 16); t += __shfl_xor(t, 32);
    if(lane == 0) gpart[wid*96 + c] = t;
  }
  __syncthreads();
  for(int c = threadIdx.x; c < CC; c += 256)
    atomicAdd(&gap[b*96 + c],
              (gpart[c] + gpart[96+c] + gpart[192+c] + gpart[288+c]) * (1.0f/4096.0f));
}

// ---- channel attention ----
__global__ void ca_kernel(const float* __restrict__ gap, const float* __restrict__ w1,
                          const float* __restrict__ b1, const float* __restrict__ w2,
                          const float* __restrict__ b2, float* __restrict__ ca){
  int b = blockIdx.x; int o = threadIdx.x;
  __shared__ float g[96], t[96];
  if(o < 96) g[o] = gap[b*96 + o];
  __syncthreads();
  if(o < 96){
    float a = b1[o];
    for(int c = 0; c < 96; ++c) a = fmaf(g[c], w1[o*96 + c], a);
    t[o] = gelu_f(a);
  }
  __syncthreads();
  if(o < 96){
    float a = b2[o];
    for(int c = 0; c < 96; ++c) a = fmaf(t[c], w2[o*96 + c], a);
    ca[b*96 + o] = sigmoid_f(a);
  }
}

extern "C" void kernel_launch(void* const* d_in, const int* in_sizes, int n_in,
                              void* d_out, int out_size, void* d_ws, size_t ws_size,
                              hipStream_t stream){
  (void)in_sizes; (void)n_in; (void)out_size; (void)ws_size;
  const float* x     = (const float*)d_in[0];
  const float* lnw   = (const float*)d_in[1];
  const float* lnb   = (const float*)d_in[2];
  const float* m1w   = (const float*)d_in[3];
  const float* m1b   = (const float*)d_in[4];
  const float* m2w   = (const float*)d_in[5];
  const float* m2b   = (const float*)d_in[6];
  const float* qkv1w = (const float*)d_in[7];
  const float* qkv1b = (const float*)d_in[8];
  const float* proj1w= (const float*)d_in[9];
  const float* proj1b= (const float*)d_in[10];
  const float* rpb1  = (const float*)d_in[11];
  const float* qkv2w = (const float*)d_in[12];
  const float* qkv2b = (const float*)d_in[13];
  const float* proj2w= (const float*)d_in[14];
  const float* proj2b= (const float*)d_in[15];
  const float* rpb2  = (const float*)d_in[16];
  const float* mw1   = (const float*)d_in[17];
  const float* mb1   = (const float*)d_in[18];
  const float* mw2   = (const float*)d_in[19];
  const float* mb2   = (const float*)d_in[20];
  const float* bng   = (const float*)d_in[21];
  const float* bnb   = (const float*)d_in[22];
  const float* bnm   = (const float*)d_in[23];
  const float* bnv   = (const float*)d_in[24];
  const float* paw1  = (const float*)d_in[25];
  const float* pab1  = (const float*)d_in[26];
  const float* paw2  = (const float*)d_in[27];
  const float* pab2  = (const float*)d_in[28];
  const float* caw1  = (const float*)d_in[29];
  const float* cab1  = (const float*)d_in[30];
  const float* caw2  = (const float*)d_in[31];
  const float* cab2  = (const float*)d_in[32];
  const float* aw1   = (const float*)d_in[33];
  const float* ab1   = (const float*)d_in[34];
  const float* aw2   = (const float*)d_in[35];
  const float* ab2   = (const float*)d_in[36];

  float* ws  = (float*)d_ws;
  float* out = (float*)d_out;
  float* st0 = ws + WS_STATS;
  float* st1 = st0 + 8;
  float* st2 = st0 + 16;
  unsigned short* q     = (unsigned short*)(ws + WS_Q);
  unsigned short* k     = (unsigned short*)(ws + WS_K);
  unsigned short* v     = (unsigned short*)(ws + WS_V);
  unsigned short* attpm = (unsigned short*)(ws + WS_ATTPM);
  unsigned short* hid   = (unsigned short*)(ws + WS_Q);   // stage-3 reuse
  float* x1  = ws + WS_X1;
  float* x2  = ws + WS_X2;
  float* x3  = ws + WS_X3;
  float* pab = ws + WS_PA;
  float* gpb = ws + WS_GAP;
  float* cab = ws + WS_CA;
  float* bns = ws + WBNS;

  hipMemsetAsync(d_ws, 0, 64*sizeof(float), stream);
  hipMemsetAsync((void*)(ws + WS_GAP), 0, 384*sizeof(float), stream);
  prep_weights<<<653, 256, 0, stream>>>(qkv1w, qkv2w, proj1w, proj2w, mw1, mw2, aw1, aw2,
                                        paw1, bng, bnb, bnm, bnv, ws);

  // stage 1: attn k=7 d=1
  stats_kernel<<<384, 256, 0, stream>>>(x, st0);
  gemm_qkv_kernel<<<256, 256, 0, stream>>>(x, st0, lnw, lnb, (unsigned short*)(ws+WQKV1), qkv1b, q, k, v);
  attn_kernel<7,1,13><<<1536, 256, 0, stream>>>(q, k, v, rpb1, attpm);
  gemm_proj_kernel<<<dim3(128,2), 256, 0, stream>>>(attpm, (unsigned short*)(ws+WPROJ1), proj1b,
                                                    x, st0, m1w, m1b, m2w, m2b, x1, st1);

  // stage 2: attn k=5 d=8
  gemm_qkv_kernel<<<256, 256, 0, stream>>>(x1, st1, lnw, lnb, (unsigned short*)(ws+WQKV2), qkv2b, q, k, v);
  attn_kernel<5,8,9><<<1536, 256, 0, stream>>>(q, k, v, rpb2, attpm);
  gemm_proj_kernel<<<dim3(128,2), 256, 0, stream>>>(attpm, (unsigned short*)(ws+WPROJ2), proj2b,
                                                    x1, st1, m1w, m1b, m2w, m2b, x2, st2);

  // stage 3: MLP (sc = x1)
  gemm_mlp1_kernel<<<256, 256, 0, stream>>>(x2, st2, lnw, lnb, (unsigned short*)(ws+WMLP1), mb1, hid);
  gemm_mlp2_kernel<<<dim3(128,2), 256, 0, stream>>>(hid, (unsigned short*)(ws+WMLP2), mb2,
                                                    x1, st2, m1w, m1b, m2w, m2b, x3);

  // stage 4: pa(+gap) -> ca -> fused m2a
  pa_gap_kernel<<<64, 256, 0, stream>>>(x3, bns, ws + WPA1T, pab1, paw2, pab2, pab, gpb);
  ca_kernel<<<4, 128, 0, stream>>>(gpb, caw1, cab1, caw2, cab2, cab);
  gemm_m2a_kernel<<<256, 256, 0, stream>>>(x3, bns, pab, cab, (unsigned short*)(ws+WM2A1), ab1,
                                           (unsigned short*)(ws+WM2A2), ab2, x3, out);
}

// Round 8
// 290.927 us; speedup vs baseline: 1.1113x; 1.1113x over previous
//
#include <hip/hip_runtime.h>
#include <math.h>

#define CC 96
#define NP 4096
#define NHEADS 6
#define NELEMF 393216.0f
#define EPSF 1e-5f

typedef __attribute__((ext_vector_type(8))) short bf16x8;
typedef __attribute__((ext_vector_type(4))) float f32x4;
#define MFMA16(a,b,c) __builtin_amdgcn_mfma_f32_16x16x32_bf16(a,b,c,0,0,0)

// ---- workspace layout (float offsets) ----
#define WS_STATS 0
#define WQKV1  64
#define WQKV2  (WQKV1+13824)
#define WPROJ1 (WQKV2+13824)
#define WPROJ2 (WPROJ1+4608)
#define WMLP1  (WPROJ2+4608)
#define WMLP2  (WMLP1+18432)
#define WM2A1  (WMLP2+18432)
#define WM2A2  (WM2A1+4608)
#define WPA1T  (WM2A2+4608)
#define WBNS   (WPA1T+1152)
#define WS_Q   870784
#define WS_K   (WS_Q+786432)
#define WS_V   (WS_K+786432)
#define WS_ATTPM (WS_V+786432)
#define WS_X1  (WS_ATTPM+786432)  // hid (bf16 16384x384) reuses WS_Q..WS_X1
#define WS_X2  (WS_X1+1572864)
#define WS_X3  (WS_X2+1572864)
#define WS_PA  (WS_X3+1572864)
#define WS_GAP (WS_PA+16384)
#define WS_CA  (WS_GAP+384)

__device__ __forceinline__ float gelu_f(float x){
  return 0.5f * x * (1.0f + erff(x * 0.7071067811865476f));
}
__device__ __forceinline__ float sigmoid_f(float x){
  return 1.0f / (1.0f + __expf(-x));
}
__device__ __forceinline__ unsigned short bfr(float f){
  unsigned int u = __float_as_uint(f);
  u += 0x7fffu + ((u >> 16) & 1u);
  return (unsigned short)(u >> 16);
}
__device__ __forceinline__ float bflo(unsigned int u){ return __uint_as_float(u << 16); }
__device__ __forceinline__ float bfhi(unsigned int u){ return __uint_as_float(u & 0xffff0000u); }
__device__ __forceinline__ void get_ms(const float* st, int b, float& mean, float& inv, float& stdv){
  float s = st[b], s2 = st[4+b];
  mean = s * (1.0f/NELEMF);
  float var = fmaxf(s2 * (1.0f/NELEMF) - mean*mean, 0.0f);
  stdv = sqrtf(var + EPSF);
  inv = 1.0f / stdv;
}

// ---- per-batch sum/sumsq over input x ----
__global__ void stats_kernel(const float* __restrict__ src, float* __restrict__ st){
  int b = blockIdx.x / CC, c = blockIdx.x % CC;
  const float* p = src + (b*CC + c)*NP;
  float s = 0.f, s2 = 0.f;
  for(int i = threadIdx.x; i < NP; i += 256){ float v = p[i]; s += v; s2 = fmaf(v, v, s2); }
  for(int off = 32; off > 0; off >>= 1){ s += __shfl_down(s, off); s2 += __shfl_down(s2, off); }
  __shared__ float ls[8];
  int wid = threadIdx.x >> 6;
  if((threadIdx.x & 63) == 0){ ls[wid] = s; ls[4+wid] = s2; }
  __syncthreads();
  if(threadIdx.x == 0){
    atomicAdd(&st[b],   ls[0]+ls[1]+ls[2]+ls[3]);
    atomicAdd(&st[4+b], ls[4]+ls[5]+ls[6]+ls[7]);
  }
}

// ---- convert all weights to bf16 W^T[n][k]; BN scale/shift; pa1 transpose ----
__global__ void prep_weights(const float* __restrict__ q1, const float* __restrict__ q2,
                             const float* __restrict__ p1, const float* __restrict__ p2,
                             const float* __restrict__ w1, const float* __restrict__ w2,
                             const float* __restrict__ a1, const float* __restrict__ a2,
                             const float* __restrict__ pw1,
                             const float* __restrict__ bg, const float* __restrict__ bb,
                             const float* __restrict__ bm, const float* __restrict__ bv,
                             float* __restrict__ ws){
  int gid = blockIdx.x*256 + threadIdx.x;
  if(gid < 27648){ int n = gid/96, c = gid%96; ((unsigned short*)(ws+WQKV1))[gid] = bfr(q1[c*288+n]); }
  else if(gid < 55296){ int g = gid-27648; int n = g/96, c = g%96; ((unsigned short*)(ws+WQKV2))[g] = bfr(q2[c*288+n]); }
  else if(gid < 64512){ int g = gid-55296; int n = g/96, c = g%96; ((unsigned short*)(ws+WPROJ1))[g] = bfr(p1[c*96+n]); }
  else if(gid < 73728){ int g = gid-64512; int n = g/96, c = g%96; ((unsigned short*)(ws+WPROJ2))[g] = bfr(p2[c*96+n]); }
  else if(gid < 110592){ int g = gid-73728; ((unsigned short*)(ws+WMLP1))[g] = bfr(w1[g]); }
  else if(gid < 147456){ int g = gid-110592; ((unsigned short*)(ws+WMLP2))[g] = bfr(w2[g]); }
  else if(gid < 156672){ int g = gid-147456; ((unsigned short*)(ws+WM2A1))[g] = bfr(a1[g]); }
  else if(gid < 165888){ int g = gid-156672; ((unsigned short*)(ws+WM2A2))[g] = bfr(a2[g]); }
  else if(gid < 167040){ int g = gid-165888; int c = g/12, h = g%12; ws[WPA1T + g] = pw1[h*96+c]; }
  else if(gid < 167136){ int c = gid-167040;
    float sc = rsqrtf(bv[c] + EPSF) * bg[c];
    ws[WBNS + c] = sc;
    ws[WBNS + 96 + c] = bb[c] - bm[c]*sc;
  }
}

// ---- fused LN + QKV GEMM: M=64-px block, all 288 N, A read once ----
__global__ void __launch_bounds__(256) gemm_qkv_kernel(
    const float* __restrict__ xin, const float* __restrict__ st,
    const float* __restrict__ lnw, const float* __restrict__ lnb,
    const unsigned short* __restrict__ wT, const float* __restrict__ qb,
    unsigned short* __restrict__ qo, unsigned short* __restrict__ ko, unsigned short* __restrict__ vo){
  __shared__ unsigned short Atl[64*104];
  __shared__ float scl[96], ofs[96];
  int m_base = blockIdx.x*64;
  int b = m_base >> 12, pxl0 = m_base & 4095;
  float mean, inv, stdv; get_ms(st, b, mean, inv, stdv);
  int tid = threadIdx.x;
  if(tid < 96){ float s = inv*lnw[tid]; scl[tid] = s; ofs[tid] = lnb[tid] - mean*s; }
  __syncthreads();
  const float* src = xin + (size_t)b*CC*NP + pxl0;
  for(int idx = tid; idx < 96*64; idx += 256){
    int c = idx >> 6, p = idx & 63;
    Atl[p*104 + c] = bfr(fmaf(src[c*NP + p], scl[c], ofs[c]));
  }
  __syncthreads();
  int w = tid >> 6, lane = tid & 63, ml = lane & 15, q = lane >> 4;
  const unsigned short* arow = Atl + (w*16 + ml)*104;
  bf16x8 av[3];
  #pragma unroll
  for(int ks = 0; ks < 3; ++ks) av[ks] = *(const bf16x8*)(arow + ks*32 + q*8);
  f32x4 z = {0.f,0.f,0.f,0.f};
  #pragma unroll
  for(int g = 0; g < 6; ++g){
    f32x4 acc[3] = {z, z, z};
    #pragma unroll
    for(int ks = 0; ks < 3; ++ks){
      #pragma unroll
      for(int gg = 0; gg < 3; ++gg){
        bf16x8 bv = *(const bf16x8*)(wT + (g*48 + gg*16 + ml)*96 + ks*32 + q*8);
        acc[gg] = MFMA16(av[ks], bv, acc[gg]);
      }
    }
    #pragma unroll
    for(int gg = 0; gg < 3; ++gg){
      int nfb = g*48 + gg*16;
      int t = nfb/96, head = (nfb%96) >> 4;
      float scale = (t == 0) ? 0.25f : 1.0f;
      unsigned short* dst = (t == 0) ? qo : (t == 1) ? ko : vo;
      float bias = qb[nfb + ml];
      #pragma unroll
      for(int r = 0; r < 4; ++r){
        int pxl = pxl0 + w*16 + q*4 + r;
        dst[(((size_t)(b*NHEADS + head))*NP + pxl)*16 + ml] = bfr((acc[gg][r] + bias)*scale);
      }
    }
  }
}

// ---- proj GEMM: attpm @ projT -> c-major + residual + fused stats (M=128) ----
__global__ void __launch_bounds__(256) gemm_proj_kernel(
    const unsigned short* __restrict__ attpm, const unsigned short* __restrict__ wT,
    const float* __restrict__ pb, const float* __restrict__ scx, const float* __restrict__ st,
    const float* __restrict__ m1w, const float* __restrict__ m1b,
    const float* __restrict__ m2w, const float* __restrict__ m2b,
    float* __restrict__ dst, float* __restrict__ st_out){
  int w = threadIdx.x >> 6, lane = threadIdx.x & 63;
  int ml = lane & 15, q = lane >> 4;
  int m_base = blockIdx.x*128 + w*32;
  int n0 = blockIdx.y*48;
  f32x4 acc[2][3];
  f32x4 z = {0.f,0.f,0.f,0.f};
  #pragma unroll
  for(int f=0; f<2; ++f) for(int g=0; g<3; ++g) acc[f][g] = z;
  {
    const bf16x8* a0 = (const bf16x8*)(attpm + (size_t)(m_base + ml)*96 + q*8);
    const bf16x8* a1 = (const bf16x8*)(attpm + (size_t)(m_base + 16 + ml)*96 + q*8);
    #pragma unroll
    for(int ks = 0; ks < 3; ++ks){
      bf16x8 av0 = a0[ks*4], av1 = a1[ks*4];
      #pragma unroll
      for(int g = 0; g < 3; ++g){
        bf16x8 bv = *(const bf16x8*)(wT + (n0 + g*16 + ml)*96 + ks*32 + q*8);
        acc[0][g] = MFMA16(av0, bv, acc[0][g]);
        acc[1][g] = MFMA16(av1, bv, acc[1][g]);
      }
    }
  }
  __shared__ float T[48*133];
  #pragma unroll
  for(int f = 0; f < 2; ++f)
    #pragma unroll
    for(int g = 0; g < 3; ++g)
      #pragma unroll
      for(int r = 0; r < 4; ++r)
        T[(g*16 + ml)*133 + w*32 + f*16 + q*4 + r] = acc[f][g][r];
  __syncthreads();
  int b = (blockIdx.x*128) >> 12, pxl0 = (blockIdx.x*128) & 4095;
  float mean, inv, stdv; get_ms(st, b, mean, inv, stdv);
  float s = 0.f, s2 = 0.f;
  for(int idx = threadIdx.x; idx < 48*128; idx += 256){
    int row = idx >> 7, px = idx & 127;
    int n = n0 + row;
    float rsf = fmaf(m1w[n], stdv, m1b[n]);
    float rbf = fmaf(m2w[n], mean, m2b[n]);
    int ad = (b*CC + n)*NP + pxl0 + px;
    float val = scx[ad] + (T[row*133 + px] + pb[n])*rsf + rbf;
    dst[ad] = val;
    s += val; s2 = fmaf(val, val, s2);
  }
  for(int off = 32; off > 0; off >>= 1){ s += __shfl_down(s, off); s2 += __shfl_down(s2, off); }
  __shared__ float ls[8];
  int wid = threadIdx.x >> 6;
  if((threadIdx.x & 63) == 0){ ls[wid] = s; ls[4+wid] = s2; }
  __syncthreads();
  if(threadIdx.x == 0){
    atomicAdd(&st_out[b],   ls[0]+ls[1]+ls[2]+ls[3]);
    atomicAdd(&st_out[4+b], ls[4]+ls[5]+ls[6]+ls[7]);
  }
}

// ---- fused LN + mlp1 GEMM: M=64, all 384 N -> relu -> hid bf16 [16384][384] ----
__global__ void __launch_bounds__(256) gemm_mlp1_kernel(
    const float* __restrict__ xin, const float* __restrict__ st,
    const float* __restrict__ lnw, const float* __restrict__ lnb,
    const unsigned short* __restrict__ wT, const float* __restrict__ b1,
    unsigned short* __restrict__ hid){
  __shared__ unsigned short Atl[64*104];
  __shared__ float scl[96], ofs[96];
  int m_base = blockIdx.x*64;
  int b = m_base >> 12, pxl0 = m_base & 4095;
  float mean, inv, stdv; get_ms(st, b, mean, inv, stdv);
  int tid = threadIdx.x;
  if(tid < 96){ float s = inv*lnw[tid]; scl[tid] = s; ofs[tid] = lnb[tid] - mean*s; }
  __syncthreads();
  const float* src = xin + (size_t)b*CC*NP + pxl0;
  for(int idx = tid; idx < 96*64; idx += 256){
    int c = idx >> 6, p = idx & 63;
    Atl[p*104 + c] = bfr(fmaf(src[c*NP + p], scl[c], ofs[c]));
  }
  __syncthreads();
  int w = tid >> 6, lane = tid & 63, ml = lane & 15, q = lane >> 4;
  const unsigned short* arow = Atl + (w*16 + ml)*104;
  bf16x8 av[3];
  #pragma unroll
  for(int ks = 0; ks < 3; ++ks) av[ks] = *(const bf16x8*)(arow + ks*32 + q*8);
  f32x4 z = {0.f,0.f,0.f,0.f};
  #pragma unroll
  for(int g = 0; g < 8; ++g){
    f32x4 acc[3] = {z, z, z};
    #pragma unroll
    for(int ks = 0; ks < 3; ++ks){
      #pragma unroll
      for(int gg = 0; gg < 3; ++gg){
        bf16x8 bv = *(const bf16x8*)(wT + (g*48 + gg*16 + ml)*96 + ks*32 + q*8);
        acc[gg] = MFMA16(av[ks], bv, acc[gg]);
      }
    }
    #pragma unroll
    for(int gg = 0; gg < 3; ++gg){
      int n = g*48 + gg*16 + ml;
      float bias = b1[n];
      #pragma unroll
      for(int r = 0; r < 4; ++r){
        int m = m_base + w*16 + q*4 + r;
        hid[(size_t)m*384 + n] = bfr(fmaxf(acc[gg][r] + bias, 0.f));
      }
    }
  }
}

// ---- mlp2 GEMM (K=384): hid @ mlp2T -> c-major + residual(x1) via st2 ----
__global__ void __launch_bounds__(256) gemm_mlp2_kernel(
    const unsigned short* __restrict__ hid, const unsigned short* __restrict__ wT,
    const float* __restrict__ b2, const float* __restrict__ scx, const float* __restrict__ st,
    const float* __restrict__ m1w, const float* __restrict__ m1b,
    const float* __restrict__ m2w, const float* __restrict__ m2b,
    float* __restrict__ dst){
  int w = threadIdx.x >> 6, lane = threadIdx.x & 63;
  int ml = lane & 15, q = lane >> 4;
  int m_base = blockIdx.x*128 + w*32;
  int n0 = blockIdx.y*48;
  f32x4 acc[2][3];
  f32x4 z = {0.f,0.f,0.f,0.f};
  #pragma unroll
  for(int f=0; f<2; ++f) for(int g=0; g<3; ++g) acc[f][g] = z;
  {
    const bf16x8* a0 = (const bf16x8*)(hid + (size_t)(m_base + ml)*384 + q*8);
    const bf16x8* a1 = (const bf16x8*)(hid + (size_t)(m_base + 16 + ml)*384 + q*8);
    #pragma unroll
    for(int ks = 0; ks < 12; ++ks){
      bf16x8 av0 = a0[ks*4], av1 = a1[ks*4];
      #pragma unroll
      for(int g = 0; g < 3; ++g){
        bf16x8 bv = *(const bf16x8*)(wT + (n0 + g*16 + ml)*384 + ks*32 + q*8);
        acc[0][g] = MFMA16(av0, bv, acc[0][g]);
        acc[1][g] = MFMA16(av1, bv, acc[1][g]);
      }
    }
  }
  __shared__ float T[48*133];
  #pragma unroll
  for(int f = 0; f < 2; ++f)
    #pragma unroll
    for(int g = 0; g < 3; ++g)
      #pragma unroll
      for(int r = 0; r < 4; ++r)
        T[(g*16 + ml)*133 + w*32 + f*16 + q*4 + r] = acc[f][g][r];
  __syncthreads();
  int b = (blockIdx.x*128) >> 12, pxl0 = (blockIdx.x*128) & 4095;
  float mean, inv, stdv; get_ms(st, b, mean, inv, stdv);
  for(int idx = threadIdx.x; idx < 48*128; idx += 256){
    int row = idx >> 7, px = idx & 127;
    int n = n0 + row;
    float rsf = fmaf(m1w[n], stdv, m1b[n]);
    float rbf = fmaf(m2w[n], mean, m2b[n]);
    int ad = (b*CC + n)*NP + pxl0 + px;
    dst[ad] = scx[ad] + (T[row*133 + px] + b2[n])*rsf + rbf;
  }
}

// ---- fused m2a: BN*pa*ca load -> GEMM1 -> gelu(LDS) -> GEMM2 -> +x3 -> out (M=64) ----
__global__ void __launch_bounds__(256) gemm_m2a_kernel(
    const float* __restrict__ x3, const float* __restrict__ bns,
    const float* __restrict__ pa, const float* __restrict__ ca,
    const unsigned short* __restrict__ w1T, const float* __restrict__ b1,
    const unsigned short* __restrict__ w2T, const float* __restrict__ b2,
    const float* __restrict__ scx, float* __restrict__ outp){
  __shared__ __align__(16) char smbuf[26624];
  __shared__ float scl[96], ofs[96], pal[64];
  unsigned short* Atl = (unsigned short*)smbuf;
  unsigned short* tl2 = (unsigned short*)(smbuf + 13312);
  float* T = (float*)smbuf;
  int m_base = blockIdx.x*64;
  int b = m_base >> 12, pxl0 = m_base & 4095;
  int tid = threadIdx.x;
  if(tid < 96){ float cv = ca[b*96 + tid]; scl[tid] = bns[tid]*cv; ofs[tid] = bns[96+tid]*cv; }
  if(tid >= 128 && tid < 192) pal[tid-128] = pa[m_base + (tid-128)];
  __syncthreads();
  const float* src = x3 + (size_t)b*CC*NP + pxl0;
  for(int idx = tid; idx < 96*64; idx += 256){
    int c = idx >> 6, p = idx & 63;
    Atl[p*104 + c] = bfr(fmaf(src[c*NP + p], scl[c], ofs[c]) * pal[p]);
  }
  __syncthreads();
  int w = tid >> 6, lane = tid & 63, ml = lane & 15, q = lane >> 4;
  f32x4 z = {0.f,0.f,0.f,0.f};
  f32x4 acc1[6];
  #pragma unroll
  for(int g=0; g<6; ++g) acc1[g] = z;
  {
    const unsigned short* arow = Atl + (w*16 + ml)*104;
    #pragma unroll
    for(int ks = 0; ks < 3; ++ks){
      bf16x8 av = *(const bf16x8*)(arow + ks*32 + q*8);
      #pragma unroll
      for(int g = 0; g < 6; ++g){
        bf16x8 bv = *(const bf16x8*)(w1T + (g*16 + ml)*96 + ks*32 + q*8);
        acc1[g] = MFMA16(av, bv, acc1[g]);
      }
    }
  }
  #pragma unroll
  for(int g = 0; g < 6; ++g){
    float bias = b1[g*16 + ml];
    #pragma unroll
    for(int r = 0; r < 4; ++r)
      tl2[(w*16 + q*4 + r)*104 + g*16 + ml] = bfr(gelu_f(acc1[g][r] + bias));
  }
  __syncthreads();
  f32x4 acc2[6];
  #pragma unroll
  for(int g=0; g<6; ++g) acc2[g] = z;
  {
    const unsigned short* arow = tl2 + (w*16 + ml)*104;
    #pragma unroll
    for(int ks = 0; ks < 3; ++ks){
      bf16x8 av = *(const bf16x8*)(arow + ks*32 + q*8);
      #pragma unroll
      for(int g = 0; g < 6; ++g){
        bf16x8 bv = *(const bf16x8*)(w2T + (g*16 + ml)*96 + ks*32 + q*8);
        acc2[g] = MFMA16(av, bv, acc2[g]);
      }
    }
  }
  __syncthreads();
  #pragma unroll
  for(int g = 0; g < 6; ++g)
    #pragma unroll
    for(int r = 0; r < 4; ++r)
      T[(g*16 + ml)*68 + w*16 + q*4 + r] = acc2[g][r];
  __syncthreads();
  for(int idx = tid; idx < 96*64; idx += 256){
    int n = idx >> 6, p = idx & 63;
    int ad = (b*CC + n)*NP + pxl0 + p;
    outp[ad] = scx[ad] + T[n*68 + p] + b2[n];
  }
}

// ---- neighborhood attention: bf16 LDS-staged k/v, output pixel-major bf16 ----
template<int K, int D, int RPB>
__global__ void __launch_bounds__(256) attn_kernel(
    const unsigned short* __restrict__ qb, const unsigned short* __restrict__ kb,
    const unsigned short* __restrict__ vb, const float* __restrict__ rpb,
    unsigned short* __restrict__ outp){
  int bh = blockIdx.x >> 6;
  int x = blockIdx.x & 63;
  int head = bh % NHEADS, b = bh / NHEADS;

  int gx = x % D, px = x / D;
  int Lgx = (64 - gx + D - 1) / D;
  int sx = min(max(px - K/2, 0), Lgx - K);

  __shared__ unsigned int sm[2*K*512];
  unsigned int* kl = sm;
  unsigned int* vl = sm + K*512;
  const unsigned int* kg = (const unsigned int*)(kb + (size_t)bh*NP*16);
  const unsigned int* vg = (const unsigned int*)(vb + (size_t)bh*NP*16);
  int tid = threadIdx.x;
  #pragma unroll
  for(int i = 0; i < K; ++i){
    int hh = gx + D*(sx + i);
    ((uint2*)(kl + i*512))[tid] = ((const uint2*)(kg + hh*512))[tid];
    ((uint2*)(vl + i*512))[tid] = ((const uint2*)(vg + hh*512))[tid];
  }
  __syncthreads();

  int pixoff = tid >> 2, t = tid & 3;
  int y = pixoff;
  int pix = x*64 + y;
  uint2 qd = *(const uint2*)(qb + ((size_t)bh*NP + pix)*16 + 4*t);
  float qx = bflo(qd.x), qy = bfhi(qd.x), qz = bflo(qd.y), qw = bfhi(qd.y);

  int gy = y % D, py = y / D;
  int Lgy = (64 - gy + D - 1) / D;
  int sy = min(max(py - K/2, 0), Lgy - K);

  float sc[K*K];
  #pragma unroll
  for(int i = 0; i < K; ++i){
    #pragma unroll
    for(int j = 0; j < K; ++j){
      int ww = gy + D*(sy + j);
      uint2 kv = *(const uint2*)(kl + i*512 + ww*8 + t*2);
      float s = qx*bflo(kv.x);
      s = fmaf(qy, bfhi(kv.x), s);
      s = fmaf(qz, bflo(kv.y), s);
      s = fmaf(qw, bfhi(kv.y), s);
      sc[i*K + j] = s;
    }
  }
  float mx = -1e30f;
  #pragma unroll
  for(int i = 0; i < K; ++i){
    const float* brow = rpb + (head*RPB + (sx + i - px + (K-1)))*RPB + (sy - py + (K-1));
    #pragma unroll
    for(int j = 0; j < K; ++j){
      float s = sc[i*K + j];
      s += __shfl_xor(s, 1);
      s += __shfl_xor(s, 2);
      s += brow[j];
      sc[i*K + j] = s;
      mx = fmaxf(mx, s);
    }
  }
  float sum = 0.f;
  #pragma unroll
  for(int n = 0; n < K*K; ++n){ float e = __expf(sc[n] - mx); sc[n] = e; sum += e; }
  float rs = 1.0f / sum;
  float4 acc = {0,0,0,0};
  #pragma unroll
  for(int i = 0; i < K; ++i){
    #pragma unroll
    for(int j = 0; j < K; ++j){
      int ww = gy + D*(sy + j);
      float wgt = sc[i*K + j] * rs;
      uint2 vv = *(const uint2*)(vl + i*512 + ww*8 + t*2);
      acc.x = fmaf(wgt, bflo(vv.x), acc.x);
      acc.y = fmaf(wgt, bfhi(vv.x), acc.y);
      acc.z = fmaf(wgt, bflo(vv.y), acc.z);
      acc.w = fmaf(wgt, bfhi(vv.y), acc.w);
    }
  }
  ushort4 o4;
  o4.x = bfr(acc.x); o4.y = bfr(acc.y); o4.z = bfr(acc.z); o4.w = bfr(acc.w);
  *(ushort4*)(outp + ((size_t)(b*NP + pix))*96 + head*16 + 4*t) = o4;
}

// ---- pixel attention: 4 lanes per pixel (lane owns 24 channels), 256 blocks ----
__global__ void __launch_bounds__(256) pa_kernel(
    const float* __restrict__ x3, const float* __restrict__ bns,
    const float* __restrict__ w1t, const float* __restrict__ b1,
    const float* __restrict__ w2, const float* __restrict__ b2,
    float* __restrict__ pa){
  int b = blockIdx.x >> 6;
  int px0 = (blockIdx.x & 63)*64;
  int pxq = threadIdx.x >> 2, t = threadIdx.x & 3;
  int p = px0 + pxq;
  float acc[12];
  #pragma unroll
  for(int h = 0; h < 12; ++h) acc[h] = 0.f;
  #pragma unroll 6
  for(int cc = 0; cc < 24; ++cc){
    int c = t*24 + cc;
    float yv = fmaf(x3[(b*CC + c)*NP + p], bns[c], bns[96 + c]);
    #pragma unroll
    for(int h = 0; h < 12; ++h) acc[h] = fmaf(yv, w1t[c*12 + h], acc[h]);
  }
  #pragma unroll
  for(int h = 0; h < 12; ++h){
    acc[h] += __shfl_xor(acc[h], 1);
    acc[h] += __shfl_xor(acc[h], 2);
  }
  float s = b2[0];
  #pragma unroll
  for(int h = 0; h < 12; ++h) s = fmaf(gelu_f(acc[h] + b1[h]), w2[h], s);
  if(t == 0) pa[b*NP + p] = sigmoid_f(s);
}

// ---- global average pool of pa*BN(x3): one block per (b,c), direct write ----
__global__ void gap_kernel(const float* __restrict__ x3, const float* __restrict__ bns,
                           const float* __restrict__ pa, float* __restrict__ gap){
  int b = blockIdx.x / CC, c = blockIdx.x % CC;
  float scb = bns[c], shb = bns[96 + c];
  float s = 0.f;
  for(int i = threadIdx.x; i < NP; i += 256)
    s = fmaf(fmaf(x3[(b*CC + c)*NP + i], scb, shb), pa[b*NP + i], s);
  for(int off = 32; off > 0; off >>= 1) s += __shfl_down(s, off);
  __shared__ float ls[4];
  if((threadIdx.x & 63) == 0) ls[threadIdx.x >> 6] = s;
  __syncthreads();
  if(threadIdx.x == 0) gap[blockIdx.x] = (ls[0]+ls[1]+ls[2]+ls[3]) * (1.0f/4096.0f);
}

// ---- channel attention ----
__global__ void ca_kernel(const float* __restrict__ gap, const float* __restrict__ w1,
                          const float* __restrict__ b1, const float* __restrict__ w2,
                          const float* __restrict__ b2, float* __restrict__ ca){
  int b = blockIdx.x; int o = threadIdx.x;
  __shared__ float g[96], t[96];
  if(o < 96) g[o] = gap[b*96 + o];
  __syncthreads();
  if(o < 96){
    float a = b1[o];
    for(int c = 0; c < 96; ++c) a = fmaf(g[c], w1[o*96 + c], a);
    t[o] = gelu_f(a);
  }
  __syncthreads();
  if(o < 96){
    float a = b2[o];
    for(int c = 0; c < 96; ++c) a = fmaf(t[c], w2[o*96 + c], a);
    ca[b*96 + o] = sigmoid_f(a);
  }
}

extern "C" void kernel_launch(void* const* d_in, const int* in_sizes, int n_in,
                              void* d_out, int out_size, void* d_ws, size_t ws_size,
                              hipStream_t stream){
  (void)in_sizes; (void)n_in; (void)out_size; (void)ws_size;
  const float* x     = (const float*)d_in[0];
  const float* lnw   = (const float*)d_in[1];
  const float* lnb   = (const float*)d_in[2];
  const float* m1w   = (const float*)d_in[3];
  const float* m1b   = (const float*)d_in[4];
  const float* m2w   = (const float*)d_in[5];
  const float* m2b   = (const float*)d_in[6];
  const float* qkv1w = (const float*)d_in[7];
  const float* qkv1b = (const float*)d_in[8];
  const float* proj1w= (const float*)d_in[9];
  const float* proj1b= (const float*)d_in[10];
  const float* rpb1  = (const float*)d_in[11];
  const float* qkv2w = (const float*)d_in[12];
  const float* qkv2b = (const float*)d_in[13];
  const float* proj2w= (const float*)d_in[14];
  const float* proj2b= (const float*)d_in[15];
  const float* rpb2  = (const float*)d_in[16];
  const float* mw1   = (const float*)d_in[17];
  const float* mb1   = (const float*)d_in[18];
  const float* mw2   = (const float*)d_in[19];
  const float* mb2   = (const float*)d_in[20];
  const float* bng   = (const float*)d_in[21];
  const float* bnb   = (const float*)d_in[22];
  const float* bnm   = (const float*)d_in[23];
  const float* bnv   = (const float*)d_in[24];
  const float* paw1  = (const float*)d_in[25];
  const float* pab1  = (const float*)d_in[26];
  const float* paw2  = (const float*)d_in[27];
  const float* pab2  = (const float*)d_in[28];
  const float* caw1  = (const float*)d_in[29];
  const float* cab1  = (const float*)d_in[30];
  const float* caw2  = (const float*)d_in[31];
  const float* cab2  = (const float*)d_in[32];
  const float* aw1   = (const float*)d_in[33];
  const float* ab1   = (const float*)d_in[34];
  const float* aw2   = (const float*)d_in[35];
  const float* ab2   = (const float*)d_in[36];

  float* ws  = (float*)d_ws;
  float* out = (float*)d_out;
  float* st0 = ws + WS_STATS;
  float* st1 = st0 + 8;
  float* st2 = st0 + 16;
  unsigned short* q     = (unsigned short*)(ws + WS_Q);
  unsigned short* k     = (unsigned short*)(ws + WS_K);
  unsigned short* v     = (unsigned short*)(ws + WS_V);
  unsigned short* attpm = (unsigned short*)(ws + WS_ATTPM);
  unsigned short* hid   = (unsigned short*)(ws + WS_Q);
  float* x1  = ws + WS_X1;
  float* x2  = ws + WS_X2;
  float* x3  = ws + WS_X3;
  float* pab = ws + WS_PA;
  float* gpb = ws + WS_GAP;
  float* cab = ws + WS_CA;
  float* bns = ws + WBNS;

  hipMemsetAsync(d_ws, 0, 64*sizeof(float), stream);
  prep_weights<<<653, 256, 0, stream>>>(qkv1w, qkv2w, proj1w, proj2w, mw1, mw2, aw1, aw2,
                                        paw1, bng, bnb, bnm, bnv, ws);

  // stage 1: attn k=7 d=1
  stats_kernel<<<384, 256, 0, stream>>>(x, st0);
  gemm_qkv_kernel<<<256, 256, 0, stream>>>(x, st0, lnw, lnb, (unsigned short*)(ws+WQKV1), qkv1b, q, k, v);
  attn_kernel<7,1,13><<<1536, 256, 0, stream>>>(q, k, v, rpb1, attpm);
  gemm_proj_kernel<<<dim3(128,2), 256, 0, stream>>>(attpm, (unsigned short*)(ws+WPROJ1), proj1b,
                                                    x, st0, m1w, m1b, m2w, m2b, x1, st1);

  // stage 2: attn k=5 d=8
  gemm_qkv_kernel<<<256, 256, 0, stream>>>(x1, st1, lnw, lnb, (unsigned short*)(ws+WQKV2), qkv2b, q, k, v);
  attn_kernel<5,8,9><<<1536, 256, 0, stream>>>(q, k, v, rpb2, attpm);
  gemm_proj_kernel<<<dim3(128,2), 256, 0, stream>>>(attpm, (unsigned short*)(ws+WPROJ2), proj2b,
                                                    x1, st1, m1w, m1b, m2w, m2b, x2, st2);

  // stage 3: MLP (sc = x1)
  gemm_mlp1_kernel<<<256, 256, 0, stream>>>(x2, st2, lnw, lnb, (unsigned short*)(ws+WMLP1), mb1, hid);
  gemm_mlp2_kernel<<<dim3(128,2), 256, 0, stream>>>(hid, (unsigned short*)(ws+WMLP2), mb2,
                                                    x1, st2, m1w, m1b, m2w, m2b, x3);

  // stage 4: pa -> gap -> ca -> fused m2a
  pa_kernel<<<256, 256, 0, stream>>>(x3, bns, ws + WPA1T, pab1, paw2, pab2, pab);
  gap_kernel<<<384, 256, 0, stream>>>(x3, bns, pab, gpb);
  ca_kernel<<<4, 128, 0, stream>>>(gpb, caw1, cab1, caw2, cab2, cab);
  gemm_m2a_kernel<<<256, 256, 0, stream>>>(x3, bns, pab, cab, (unsigned short*)(ws+WM2A1), ab1,
                                           (unsigned short*)(ws+WM2A2), ab2, x3, out);
}